// Round 5
// baseline (234.552 us; speedup 1.0000x reference)
//
#include <hip/hip_runtime.h>
#include <hip/hip_bf16.h>

#define DIM   1024
#define HEADS 16
#define HD    64
#define BB    2
#define LL    2048
#define MTOT  (BB*LL)   // 4096
#define EPSV  1.1920928955078125e-07f

typedef __attribute__((ext_vector_type(8))) short bf16x8;
typedef __attribute__((ext_vector_type(4))) float f32x4;
typedef unsigned short ushort_t;

__device__ __forceinline__ float bf2f(ushort_t u) {
    unsigned int x = ((unsigned int)u) << 16;
    return __builtin_bit_cast(float, x);
}
__device__ __forceinline__ ushort_t f2bf(float f) {
    unsigned int x = __builtin_bit_cast(unsigned int, f);
    unsigned int r = (x + 0x7FFFu + ((x >> 16) & 1u)) >> 16;
    return (ushort_t)r;
}

// ---------------- fp32 -> bf16 convert (vectorized) ----------------
__global__ __launch_bounds__(256) void f32_to_bf16_k(const float* __restrict__ in,
                                                     ushort_t* __restrict__ out, int n) {
    int i = (blockIdx.x * 256 + threadIdx.x) * 4;
    if (i < n) {
        float4 v = *(const float4*)(in + i);
        ushort4 o;
        o.x = f2bf(v.x); o.y = f2bf(v.y); o.z = f2bf(v.z); o.w = f2bf(v.w);
        *(ushort4*)(out + i) = o;
    }
}

// ---------------- GEMM 256x256, BK=64, 8 waves, dbuf LDS, early-staged ----------
// C[M][N] (bf16) = A[M][K] * Bt[N][K]^T + bias. M%256==0, N%256==0, K%64==0,
// grid.x = (M/256)*(N/256), must be %8==0 for the XCD swizzle.
__global__ __launch_bounds__(512, 2) void gemm256(const ushort_t* __restrict__ A,
                                                  const ushort_t* __restrict__ Bt,
                                                  const float* __restrict__ bias,
                                                  ushort_t* __restrict__ C,
                                                  int M, int N, int K) {
    __shared__ __attribute__((aligned(16))) ushort_t Asm[2][256 * 64];
    __shared__ __attribute__((aligned(16))) ushort_t Bsm[2][256 * 64];
    const int tid = threadIdx.x;
    const int lane = tid & 63, wid = tid >> 6;
    const int wm = wid >> 1, wn = wid & 1;  // 4 M-waves x 2 N-waves
    const int r = lane & 15, g = lane >> 4;

    const int mtiles = M >> 8;
    const int cpx = gridDim.x >> 3;
    const int bid = blockIdx.x;
    const int swz = (bid & 7) * cpx + (bid >> 3);   // T1 XCD swizzle (bijective: nwg%8==0)
    const int mt = swz % mtiles, nt = swz / mtiles;
    const int m0 = mt * 256, n0 = nt * 256;

    // staging geometry: half-tile = 128 rows x 64 cols; chunk c = q*512+tid
    // LDS is linear; global source col pre-swizzled by row&7 (rule #21).
    int srow[2], sgx[2];
#pragma unroll
    for (int q = 0; q < 2; ++q) {
        int c = q * 512 + tid;
        srow[q] = c >> 3;
        sgx[q] = ((c & 7) ^ (srow[q] & 7)) * 8;
    }
    const ushort_t* pa[2][2];
    const ushort_t* pb[2][2];
#pragma unroll
    for (int q = 0; q < 2; ++q)
#pragma unroll
        for (int h = 0; h < 2; ++h) {
            pa[q][h] = A + (size_t)(m0 + h * 128 + srow[q]) * K + sgx[q];
            pb[q][h] = Bt + (size_t)(n0 + h * 128 + srow[q]) * K + sgx[q];
        }

    f32x4 acc[4][8] = {};

    auto stage = [&](int kt, int slot) {
        const int kc = kt * 64;
#pragma unroll
        for (int h = 0; h < 2; ++h)
#pragma unroll
            for (int q = 0; q < 2; ++q) {
                __builtin_amdgcn_global_load_lds(
                    (const __attribute__((address_space(1))) void*)(pa[q][h] + kc),
                    (__attribute__((address_space(3))) void*)(&Asm[slot][0] + h * 8192 + (q * 512 + wid * 64) * 8),
                    16, 0, 0);
                __builtin_amdgcn_global_load_lds(
                    (const __attribute__((address_space(1))) void*)(pb[q][h] + kc),
                    (__attribute__((address_space(3))) void*)(&Bsm[slot][0] + h * 8192 + (q * 512 + wid * 64) * 8),
                    16, 0, 0);
            }
    };

    // prologue: stage K-tile 0 into slot 0
    stage(0, 0);
    asm volatile("s_waitcnt vmcnt(0)" ::: "memory");
    __builtin_amdgcn_s_barrier();
    asm volatile("" ::: "memory");

    const int nkt = K >> 6;
    for (int kt = 0; kt < nkt; ++kt) {
        const int slot = kt & 1;
        if (kt + 1 < nkt) stage(kt + 1, slot ^ 1);  // early issue; drains at boundary
        const ushort_t* As = &Asm[slot][0];
        const ushort_t* Bs = &Bsm[slot][0];
#pragma unroll
        for (int ks = 0; ks < 2; ++ks) {
            bf16x8 af[4], bf[8];
#pragma unroll
            for (int mi = 0; mi < 4; ++mi) {
                int row = wm * 64 + mi * 16 + r;
                af[mi] = *(const bf16x8*)(As + row * 64 + (((ks * 4 + g) * 8) ^ ((row & 7) * 8)));
            }
#pragma unroll
            for (int ni = 0; ni < 8; ++ni) {
                int row = wn * 128 + ni * 16 + r;
                bf[ni] = *(const bf16x8*)(Bs + row * 64 + (((ks * 4 + g) * 8) ^ ((row & 7) * 8)));
            }
            __builtin_amdgcn_s_setprio(1);
#pragma unroll
            for (int mi = 0; mi < 4; ++mi)
#pragma unroll
                for (int ni = 0; ni < 8; ++ni)
                    acc[mi][ni] = __builtin_amdgcn_mfma_f32_16x16x32_bf16(af[mi], bf[ni], acc[mi][ni], 0, 0, 0);
            __builtin_amdgcn_s_setprio(0);
        }
        // single boundary per K-tile: own stage-loads drained, then block-wide barrier
        asm volatile("s_waitcnt vmcnt(0)" ::: "memory");
        __builtin_amdgcn_s_barrier();
        asm volatile("" ::: "memory");
    }

    // epilogue: bias + bf16 store (same pattern as verified gemm_bt)
#pragma unroll
    for (int ni = 0; ni < 8; ++ni) {
        int col = n0 + wn * 128 + ni * 16 + r;
        float bv = bias[col];
#pragma unroll
        for (int mi = 0; mi < 4; ++mi)
#pragma unroll
            for (int reg = 0; reg < 4; ++reg) {
                int row = m0 + wm * 64 + mi * 16 + g * 4 + reg;
                C[(size_t)row * N + col] = f2bf(acc[mi][ni][reg] + bv);
            }
    }
}

// ---------------- GEMM: C[M][N] = A[M][K] * Bt[N][K]^T + bias (128² legacy) -----
template <int OUT_BF16>
__global__ __launch_bounds__(256) void gemm_bt(const ushort_t* __restrict__ A,
                                               const ushort_t* __restrict__ Bt,
                                               const float* __restrict__ bias,
                                               void* __restrict__ Cout,
                                               int M, int N, int K) {
    __shared__ __attribute__((aligned(16))) ushort_t Asm[128 * 32];
    __shared__ __attribute__((aligned(16))) ushort_t Bsm[128 * 32];
    int tid = threadIdx.x;
    int lane = tid & 63, wid = tid >> 6;
    int wm = wid >> 1, wn = wid & 1;
    int r = lane & 15, g = lane >> 4;
    int m0 = blockIdx.y * 128, n0 = blockIdx.x * 128;

    f32x4 acc[4][4] = {};

    int niter = K >> 5;
    for (int kk = 0; kk < niter; ++kk) {
        int k0 = kk << 5;
        __syncthreads();
#pragma unroll
        for (int p = 0; p < 2; ++p) {
            int off = (p * 256 + tid) * 8;
            int row = off >> 5, col = off & 31;
            int ldsoff = (p * 256 + wid * 64) * 8;
            __builtin_amdgcn_global_load_lds(
                (const __attribute__((address_space(1))) void*)(A + (size_t)(m0 + row) * K + k0 + col),
                (__attribute__((address_space(3))) void*)(Asm + ldsoff), 16, 0, 0);
            __builtin_amdgcn_global_load_lds(
                (const __attribute__((address_space(1))) void*)(Bt + (size_t)(n0 + row) * K + k0 + col),
                (__attribute__((address_space(3))) void*)(Bsm + ldsoff), 16, 0, 0);
        }
        __syncthreads();
        bf16x8 af[4], bfr[4];
#pragma unroll
        for (int mi = 0; mi < 4; mi++)
            af[mi] = *(const bf16x8*)(Asm + (wm * 64 + mi * 16 + r) * 32 + g * 8);
#pragma unroll
        for (int ni = 0; ni < 4; ni++)
            bfr[ni] = *(const bf16x8*)(Bsm + (wn * 64 + ni * 16 + r) * 32 + g * 8);
#pragma unroll
        for (int mi = 0; mi < 4; mi++)
#pragma unroll
            for (int ni = 0; ni < 4; ni++)
                acc[mi][ni] = __builtin_amdgcn_mfma_f32_16x16x32_bf16(af[mi], bfr[ni], acc[mi][ni], 0, 0, 0);
    }
#pragma unroll
    for (int mi = 0; mi < 4; mi++)
#pragma unroll
        for (int ni = 0; ni < 4; ni++) {
            int col = n0 + wn * 64 + ni * 16 + r;
            float bv = bias[col];
#pragma unroll
            for (int reg = 0; reg < 4; reg++) {
                int row = m0 + wm * 64 + mi * 16 + g * 4 + reg;
                float v = acc[mi][ni][reg] + bv;
                if (OUT_BF16)
                    ((ushort_t*)Cout)[(size_t)row * N + col] = f2bf(v);
                else
                    ((float*)Cout)[(size_t)row * N + col] = v;
            }
        }
}

// ---------------- RMSNorm + RoPE + scatter (vectorized, coalesced V-transpose) ---
__global__ __launch_bounds__(256) void norm_rope_k(const ushort_t* __restrict__ qkv,
                                                   const float* __restrict__ pe,
                                                   const float* __restrict__ qnw,
                                                   const float* __restrict__ knw,
                                                   ushort_t* __restrict__ qh,
                                                   ushort_t* __restrict__ kh,
                                                   ushort_t* __restrict__ vT) {
    __shared__ ushort_t T[64][68];
    const int tid = threadIdx.x;
    const int lane = tid & 63, w = tid >> 6;
    const int rg = lane >> 4;
    const int d4 = (lane & 15) * 4;
    const int l0 = blockIdx.x * 64;
    const int t  = blockIdx.y;
    const int bh = blockIdx.z;
    const int b = bh >> 4, h = bh & 15;

    if (t == 2) {  // V: bf16 copy + transpose through LDS
#pragma unroll
        for (int i = 0; i < 4; ++i) {
            int ll = w * 16 + rg + 4 * i;
            int m = b * 2048 + l0 + ll;
            ushort4 v = *(const ushort4*)(qkv + (size_t)m * 3072 + 2048 + h * 64 + d4);
            *(ushort4*)(&T[ll][d4]) = v;
        }
        __syncthreads();
        const int d = tid >> 2, lq = (tid & 3) * 16;
        ushort_t* dst = vT + ((size_t)(bh * 64 + d)) * 2048 + l0 + lq;
#pragma unroll
        for (int c = 0; c < 4; ++c) {
            ushort4 o;
            o.x = T[lq + c * 4 + 0][d];
            o.y = T[lq + c * 4 + 1][d];
            o.z = T[lq + c * 4 + 2][d];
            o.w = T[lq + c * 4 + 3][d];
            *(ushort4*)(dst + c * 4) = o;
        }
        return;
    }

    const float* nwp = (t == 0) ? qnw : knw;
    const float4 nwv = *(const float4*)(nwp + d4);
    ushort_t* dst = (t == 0) ? qh : kh;
    const float qscale = (t == 0) ? 0.125f : 1.0f;
#pragma unroll
    for (int i = 0; i < 4; ++i) {
        int ll = w * 16 + rg + 4 * i;
        int l = l0 + ll;
        int m = b * 2048 + l;
        ushort4 vv = *(const ushort4*)(qkv + (size_t)m * 3072 + t * 1024 + h * 64 + d4);
        float v0 = bf2f(vv.x), v1 = bf2f(vv.y), v2 = bf2f(vv.z), v3 = bf2f(vv.w);
        float ss = v0 * v0 + v1 * v1 + v2 * v2 + v3 * v3;
        ss += __shfl_xor(ss, 1, 64);
        ss += __shfl_xor(ss, 2, 64);
        ss += __shfl_xor(ss, 4, 64);
        ss += __shfl_xor(ss, 8, 64);
        float rms = rsqrtf(ss * (1.0f / 64.0f) + EPSV);
        v0 *= rms * nwv.x; v1 *= rms * nwv.y; v2 *= rms * nwv.z; v3 *= rms * nwv.w;
        float4 p0 = *(const float4*)(pe + (size_t)l * 128 + 2 * d4);
        float4 p1 = *(const float4*)(pe + (size_t)l * 128 + 2 * d4 + 4);
        float o0 = (p0.x * v0 + p0.y * v1) * qscale;
        float o1 = (p0.z * v0 + p0.w * v1) * qscale;
        float o2 = (p1.x * v2 + p1.y * v3) * qscale;
        float o3 = (p1.z * v2 + p1.w * v3) * qscale;
        ushort4 o;
        o.x = f2bf(o0); o.y = f2bf(o1); o.z = f2bf(o2); o.w = f2bf(o3);
        *(ushort4*)(dst + ((size_t)bh * 2048 + l) * 64 + d4) = o;
    }
}

// ---------------- Flash attention v2 + defer-max (T13) ----------------
__global__ __launch_bounds__(256, 2) void attn_k(const ushort_t* __restrict__ qh,
                                                 const ushort_t* __restrict__ kh,
                                                 const ushort_t* __restrict__ vT,
                                                 ushort_t* __restrict__ ob) {
    __shared__ __attribute__((aligned(16))) ushort_t Ksm[2][64 * 64];
    __shared__ __attribute__((aligned(16))) ushort_t Vsm[2][64 * 64];
    __shared__ __attribute__((aligned(16))) ushort_t Plds[4][2][16 * 64];

    const int tid = threadIdx.x;
    const int lane = tid & 63, wid = tid >> 6;
    const int r = lane & 15, g = lane >> 4;
    const int qt = blockIdx.x, bh = blockIdx.y;
    const int q0 = qt * 128 + wid * 32;
    const ushort_t* Q  = qh + (size_t)bh * LL * 64;
    const ushort_t* Kb = kh + (size_t)bh * LL * 64;
    const ushort_t* Vt = vT + (size_t)bh * 64 * LL;

    int row_[2], ccx_[2];
#pragma unroll
    for (int q = 0; q < 2; ++q) {
        int c = q * 256 + tid;
        row_[q] = c >> 3;
        ccx_[q] = (c & 7) ^ (row_[q] & 7);
    }
    const int swz = (r & 7) * 8;

    bf16x8 qf[2][2];
#pragma unroll
    for (int mf = 0; mf < 2; ++mf)
#pragma unroll
        for (int hf = 0; hf < 2; ++hf)
            qf[mf][hf] = *(const bf16x8*)(Q + (size_t)(q0 + mf * 16 + r) * 64 + hf * 32 + g * 8);

    f32x4 acc[2][4] = {};
    float mrow[2] = {-1e30f, -1e30f};
    float srow[2] = {0.f, 0.f};
    const f32x4 zero = {};

#pragma unroll
    for (int q = 0; q < 2; ++q) {
        __builtin_amdgcn_global_load_lds(
            (const __attribute__((address_space(1))) void*)(Kb + (size_t)row_[q] * 64 + ccx_[q] * 8),
            (__attribute__((address_space(3))) void*)(&Ksm[0][0] + (q * 256 + wid * 64) * 8), 16, 0, 0);
        __builtin_amdgcn_global_load_lds(
            (const __attribute__((address_space(1))) void*)(Vt + (size_t)row_[q] * 2048 + ccx_[q] * 8),
            (__attribute__((address_space(3))) void*)(&Vsm[0][0] + (q * 256 + wid * 64) * 8), 16, 0, 0);
    }
    __syncthreads();

    int buf = 0;
    for (int it = 0; it < 32; ++it) {
        if (it < 31) {
            int kvn = (it + 1) * 64;
#pragma unroll
            for (int q = 0; q < 2; ++q) {
                __builtin_amdgcn_global_load_lds(
                    (const __attribute__((address_space(1))) void*)(Kb + (size_t)(kvn + row_[q]) * 64 + ccx_[q] * 8),
                    (__attribute__((address_space(3))) void*)(&Ksm[buf ^ 1][0] + (q * 256 + wid * 64) * 8), 16, 0, 0);
                __builtin_amdgcn_global_load_lds(
                    (const __attribute__((address_space(1))) void*)(Vt + (size_t)row_[q] * 2048 + kvn + ccx_[q] * 8),
                    (__attribute__((address_space(3))) void*)(&Vsm[buf ^ 1][0] + (q * 256 + wid * 64) * 8), 16, 0, 0);
            }
        }
        const ushort_t* Kl = &Ksm[buf][0];
        const ushort_t* Vl = &Vsm[buf][0];

        bf16x8 kf[4][2];
#pragma unroll
        for (int kt = 0; kt < 4; ++kt)
#pragma unroll
            for (int hf = 0; hf < 2; ++hf)
                kf[kt][hf] = *(const bf16x8*)(Kl + (kt * 16 + r) * 64 + (((hf * 4 + g) * 8) ^ swz));

        f32x4 s[2][4];
        __builtin_amdgcn_s_setprio(1);
#pragma unroll
        for (int mf = 0; mf < 2; ++mf)
#pragma unroll
            for (int kt = 0; kt < 4; ++kt) {
                f32x4 t0 = __builtin_amdgcn_mfma_f32_16x16x32_bf16(kf[kt][0], qf[mf][0], zero, 0, 0, 0);
                s[mf][kt] = __builtin_amdgcn_mfma_f32_16x16x32_bf16(kf[kt][1], qf[mf][1], t0, 0, 0, 0);
            }
        __builtin_amdgcn_s_setprio(0);

#pragma unroll
        for (int mf = 0; mf < 2; ++mf) {
            float pm = -1e30f;
#pragma unroll
            for (int kt = 0; kt < 4; ++kt)
#pragma unroll
                for (int reg = 0; reg < 4; ++reg) pm = fmaxf(pm, s[mf][kt][reg]);
            pm = fmaxf(pm, __shfl_xor(pm, 16, 64));
            pm = fmaxf(pm, __shfl_xor(pm, 32, 64));
            bool skip = (__all(pm <= mrow[mf] + 8.0f) != 0);
            float mn, al;
            if (skip) {
                mn = mrow[mf];
            } else {
                mn = fmaxf(mrow[mf], pm);
                al = __expf(mrow[mf] - mn);
                mrow[mf] = mn;
            }
            float rs = 0.f;
#pragma unroll
            for (int kt = 0; kt < 4; ++kt)
#pragma unroll
                for (int reg = 0; reg < 4; ++reg) {
                    float p = __expf(s[mf][kt][reg] - mn);
                    s[mf][kt][reg] = p;
                    rs += p;
                }
            rs += __shfl_xor(rs, 16, 64);
            rs += __shfl_xor(rs, 32, 64);
            if (skip) {
                srow[mf] += rs;
            } else {
                srow[mf] = srow[mf] * al + rs;
                float ab[4];
#pragma unroll
                for (int reg = 0; reg < 4; ++reg) ab[reg] = __shfl(al, g * 4 + reg, 16);
#pragma unroll
                for (int dt = 0; dt < 4; ++dt)
#pragma unroll
                    for (int reg = 0; reg < 4; ++reg) acc[mf][dt][reg] *= ab[reg];
            }
#pragma unroll
            for (int kt = 0; kt < 4; ++kt) {
                ushort4 pw;
                pw.x = f2bf(s[mf][kt][0]); pw.y = f2bf(s[mf][kt][1]);
                pw.z = f2bf(s[mf][kt][2]); pw.w = f2bf(s[mf][kt][3]);
                *(ushort4*)(&Plds[wid][mf][0] + r * 64 + (((2 * kt + (g >> 1)) * 8) ^ swz) + (g & 1) * 4) = pw;
            }
        }
        asm volatile("s_waitcnt lgkmcnt(0)" ::: "memory");
        __builtin_amdgcn_sched_barrier(0);

        bf16x8 pa[2][2];
#pragma unroll
        for (int mf = 0; mf < 2; ++mf)
#pragma unroll
            for (int hf = 0; hf < 2; ++hf)
                pa[mf][hf] = *(const bf16x8*)(&Plds[wid][mf][0] + r * 64 + (((hf * 4 + g) * 8) ^ swz));

        __builtin_amdgcn_s_setprio(1);
#pragma unroll
        for (int dt = 0; dt < 4; ++dt)
#pragma unroll
            for (int hv = 0; hv < 2; ++hv) {
                bf16x8 vf = *(const bf16x8*)(Vl + (dt * 16 + r) * 64 + (((hv * 4 + g) * 8) ^ swz));
#pragma unroll
                for (int mf = 0; mf < 2; ++mf)
                    acc[mf][dt] = __builtin_amdgcn_mfma_f32_16x16x32_bf16(pa[mf][hv], vf, acc[mf][dt], 0, 0, 0);
            }
        __builtin_amdgcn_s_setprio(0);

        __syncthreads();
        buf ^= 1;
    }

    int b = bh >> 4, h = bh & 15;
#pragma unroll
    for (int mf = 0; mf < 2; ++mf) {
        float sinv = 1.0f / srow[mf];
        float sb[4];
#pragma unroll
        for (int reg = 0; reg < 4; ++reg) sb[reg] = __shfl(sinv, g * 4 + reg, 16);
#pragma unroll
        for (int dt = 0; dt < 4; ++dt)
#pragma unroll
            for (int reg = 0; reg < 4; ++reg) {
                int l = q0 + mf * 16 + g * 4 + reg;
                ob[((size_t)(b * 2048 + l)) * 1024 + h * 64 + dt * 16 + r] =
                    f2bf(acc[mf][dt][reg] * sb[reg]);
            }
    }
}

// ---------------- launcher ----------------
extern "C" void kernel_launch(void* const* d_in, const int* in_sizes, int n_in,
                              void* d_out, int out_size, void* d_ws, size_t ws_size,
                              hipStream_t stream) {
    const float* x      = (const float*)d_in[0];
    const float* pe     = (const float*)d_in[1];
    const float* qkv_w  = (const float*)d_in[2];
    const float* qkv_b  = (const float*)d_in[3];
    const float* qnw    = (const float*)d_in[4];
    const float* knw    = (const float*)d_in[5];
    const float* proj_w = (const float*)d_in[6];
    const float* proj_b = (const float*)d_in[7];
    float* out = (float*)d_out;

    char* ws = (char*)d_ws;
    ushort_t* xb    = (ushort_t*)(ws);                         // 8 MB
    ushort_t* wqkv  = (ushort_t*)(ws + 8388608);               // 6 MB
    ushort_t* wproj = (ushort_t*)(ws + 8388608 + 6291456);     // 2 MB
    ushort_t* qkvb  = (ushort_t*)(ws + 16777216);              // 24 MB
    ushort_t* qhp   = (ushort_t*)(ws + 16777216 + 25165824);   // 8 MB
    ushort_t* khp   = (ushort_t*)(ws + 16777216 + 25165824 + 8388608);
    ushort_t* vtp   = (ushort_t*)(ws + 16777216 + 25165824 + 2 * 8388608);
    ushort_t* obp   = qkvb;  // reuse qkv region

    f32_to_bf16_k<<<MTOT * DIM / 1024, 256, 0, stream>>>(x, xb, MTOT * DIM);
    f32_to_bf16_k<<<3 * DIM * DIM / 1024, 256, 0, stream>>>(qkv_w, wqkv, 3 * DIM * DIM);
    f32_to_bf16_k<<<DIM * DIM / 1024, 256, 0, stream>>>(proj_w, wproj, DIM * DIM);

    // QKV GEMM: 256^2 tile kernel, grid 16*12 = 192 (%8==0)
    gemm256<<<(MTOT / 256) * (3 * DIM / 256), 512, 0, stream>>>(xb, wqkv, qkv_b, qkvb,
                                                                MTOT, 3 * DIM, DIM);
    norm_rope_k<<<dim3(32, 3, 32), 256, 0, stream>>>(qkvb, pe, qnw, knw, qhp, khp, vtp);
    attn_k<<<dim3(16, 32), 256, 0, stream>>>(qhp, khp, vtp, obp);
    gemm_bt<0><<<dim3(DIM / 128, MTOT / 128), 256, 0, stream>>>(obp, wproj, proj_b, out,
                                                                MTOT, DIM, DIM);
}

// Round 6
// 217.631 us; speedup vs baseline: 1.0777x; 1.0777x over previous
//
#include <hip/hip_runtime.h>
#include <hip/hip_bf16.h>

#define DIM   1024
#define HEADS 16
#define HD    64
#define BB    2
#define LL    2048
#define MTOT  (BB*LL)   // 4096
#define EPSV  1.1920928955078125e-07f

typedef __attribute__((ext_vector_type(8))) short bf16x8;
typedef __attribute__((ext_vector_type(4))) float f32x4;
typedef unsigned short ushort_t;

__device__ __forceinline__ float bf2f(ushort_t u) {
    unsigned int x = ((unsigned int)u) << 16;
    return __builtin_bit_cast(float, x);
}
__device__ __forceinline__ ushort_t f2bf(float f) {
    unsigned int x = __builtin_bit_cast(unsigned int, f);
    unsigned int r = (x + 0x7FFFu + ((x >> 16) & 1u)) >> 16;
    return (ushort_t)r;
}
__device__ __forceinline__ unsigned int cvt_pk_bf16(float lo, float hi) {
    unsigned int r;
    asm("v_cvt_pk_bf16_f32 %0, %1, %2" : "=v"(r) : "v"(lo), "v"(hi));
    return r;
}

// ---------------- fused fp32 -> bf16 converts (x, qkv_w, proj_w) ----------------
__global__ __launch_bounds__(256) void cvt_all_k(const float* __restrict__ a, int na,
                                                 const float* __restrict__ b, int nb,
                                                 const float* __restrict__ c,
                                                 ushort_t* __restrict__ oa,
                                                 ushort_t* __restrict__ ob,
                                                 ushort_t* __restrict__ oc) {
    int i = (blockIdx.x * 256 + threadIdx.x) * 4;
    const float* src;
    ushort_t* dst;
    int off;
    if (i < na)            { src = a; dst = oa; off = i; }
    else if (i < na + nb)  { src = b; dst = ob; off = i - na; }
    else                   { src = c; dst = oc; off = i - na - nb; }
    float4 v = *(const float4*)(src + off);
    ushort4 o;
    o.x = f2bf(v.x); o.y = f2bf(v.y); o.z = f2bf(v.z); o.w = f2bf(v.w);
    *(ushort4*)(dst + off) = o;
}

// ---------------- GEMM 128x128, BK=64, dbuf LDS, early-issue, 2 blocks/CU -------
// C[M][N] (bf16) = A[M][K] * Bt[N][K]^T + bias
__global__ __launch_bounds__(256, 2) void gemm128(const ushort_t* __restrict__ A,
                                                  const ushort_t* __restrict__ Bt,
                                                  const float* __restrict__ bias,
                                                  ushort_t* __restrict__ C,
                                                  int M, int N, int K) {
    __shared__ __attribute__((aligned(16))) ushort_t Asm[2][128 * 64];
    __shared__ __attribute__((aligned(16))) ushort_t Bsm[2][128 * 64];
    const int tid = threadIdx.x;
    const int lane = tid & 63, wid = tid >> 6;
    const int wm = wid >> 1, wn = wid & 1;
    const int r = lane & 15, g = lane >> 4;
    const int m0 = blockIdx.y * 128, n0 = blockIdx.x * 128;

    // staging: 4 passes each for A,B; chunk c = p*256+tid; source col pre-swizzled
    int srow[4], sgx[4];
#pragma unroll
    for (int p = 0; p < 4; ++p) {
        int c = p * 256 + tid;
        srow[p] = c >> 3;
        sgx[p] = ((c & 7) ^ (srow[p] & 7)) * 8;
    }
    const ushort_t *pa[4], *pb[4];
#pragma unroll
    for (int p = 0; p < 4; ++p) {
        pa[p] = A + (size_t)(m0 + srow[p]) * K + sgx[p];
        pb[p] = Bt + (size_t)(n0 + srow[p]) * K + sgx[p];
    }

    f32x4 acc[4][4] = {};

    auto stage = [&](int kt, int slot) {
        const int kc = kt * 64;
#pragma unroll
        for (int p = 0; p < 4; ++p) {
            __builtin_amdgcn_global_load_lds(
                (const __attribute__((address_space(1))) void*)(pa[p] + kc),
                (__attribute__((address_space(3))) void*)(&Asm[slot][0] + (p * 256 + wid * 64) * 8), 16, 0, 0);
            __builtin_amdgcn_global_load_lds(
                (const __attribute__((address_space(1))) void*)(pb[p] + kc),
                (__attribute__((address_space(3))) void*)(&Bsm[slot][0] + (p * 256 + wid * 64) * 8), 16, 0, 0);
        }
    };

    stage(0, 0);
    asm volatile("s_waitcnt vmcnt(0)" ::: "memory");
    __builtin_amdgcn_s_barrier();
    asm volatile("" ::: "memory");

    const int nkt = K >> 6;
    for (int kt = 0; kt < nkt; ++kt) {
        const int slot = kt & 1;
        if (kt + 1 < nkt) stage(kt + 1, slot ^ 1);
        const ushort_t* As = &Asm[slot][0];
        const ushort_t* Bs = &Bsm[slot][0];
#pragma unroll
        for (int ks = 0; ks < 2; ++ks) {
            bf16x8 af[4], bf[4];
#pragma unroll
            for (int mi = 0; mi < 4; ++mi) {
                int row = wm * 64 + mi * 16 + r;
                af[mi] = *(const bf16x8*)(As + row * 64 + (((ks * 4 + g) ^ (row & 7)) * 8));
            }
#pragma unroll
            for (int ni = 0; ni < 4; ++ni) {
                int row = wn * 64 + ni * 16 + r;
                bf[ni] = *(const bf16x8*)(Bs + row * 64 + (((ks * 4 + g) ^ (row & 7)) * 8));
            }
            __builtin_amdgcn_s_setprio(1);
#pragma unroll
            for (int mi = 0; mi < 4; ++mi)
#pragma unroll
                for (int ni = 0; ni < 4; ++ni)
                    acc[mi][ni] = __builtin_amdgcn_mfma_f32_16x16x32_bf16(af[mi], bf[ni], acc[mi][ni], 0, 0, 0);
            __builtin_amdgcn_s_setprio(0);
        }
        asm volatile("s_waitcnt vmcnt(0)" ::: "memory");
        __builtin_amdgcn_s_barrier();
        asm volatile("" ::: "memory");
    }

#pragma unroll
    for (int mi = 0; mi < 4; mi++)
#pragma unroll
        for (int ni = 0; ni < 4; ni++) {
            int col = n0 + wn * 64 + ni * 16 + r;
            float bv = bias[col];
#pragma unroll
            for (int reg = 0; reg < 4; reg++) {
                int row = m0 + wm * 64 + mi * 16 + g * 4 + reg;
                C[(size_t)row * N + col] = f2bf(acc[mi][ni][reg] + bv);
            }
        }
}

// ---------------- proj GEMM 128x64, BK=64, dbuf, f32 out (grid 512 = 2/CU) ------
__global__ __launch_bounds__(256, 2) void gemm_pj(const ushort_t* __restrict__ A,
                                                  const ushort_t* __restrict__ Bt,
                                                  const float* __restrict__ bias,
                                                  float* __restrict__ C,
                                                  int M, int N, int K) {
    __shared__ __attribute__((aligned(16))) ushort_t Asm[2][128 * 64];
    __shared__ __attribute__((aligned(16))) ushort_t Bsm[2][64 * 64];
    const int tid = threadIdx.x;
    const int lane = tid & 63, wid = tid >> 6;
    const int wm = wid >> 1, wn = wid & 1;
    const int r = lane & 15, g = lane >> 4;
    const int m0 = blockIdx.y * 128, n0 = blockIdx.x * 64;

    int srow[4], sgx[4];
#pragma unroll
    for (int p = 0; p < 4; ++p) {
        int c = p * 256 + tid;
        srow[p] = c >> 3;
        sgx[p] = ((c & 7) ^ (srow[p] & 7)) * 8;
    }
    const ushort_t *pa[4], *pb[2];
#pragma unroll
    for (int p = 0; p < 4; ++p) pa[p] = A + (size_t)(m0 + srow[p]) * K + sgx[p];
#pragma unroll
    for (int p = 0; p < 2; ++p) pb[p] = Bt + (size_t)(n0 + srow[p]) * K + sgx[p];

    f32x4 acc[4][2] = {};

    auto stage = [&](int kt, int slot) {
        const int kc = kt * 64;
#pragma unroll
        for (int p = 0; p < 4; ++p)
            __builtin_amdgcn_global_load_lds(
                (const __attribute__((address_space(1))) void*)(pa[p] + kc),
                (__attribute__((address_space(3))) void*)(&Asm[slot][0] + (p * 256 + wid * 64) * 8), 16, 0, 0);
#pragma unroll
        for (int p = 0; p < 2; ++p)
            __builtin_amdgcn_global_load_lds(
                (const __attribute__((address_space(1))) void*)(pb[p] + kc),
                (__attribute__((address_space(3))) void*)(&Bsm[slot][0] + (p * 256 + wid * 64) * 8), 16, 0, 0);
    };

    stage(0, 0);
    asm volatile("s_waitcnt vmcnt(0)" ::: "memory");
    __builtin_amdgcn_s_barrier();
    asm volatile("" ::: "memory");

    const int nkt = K >> 6;
    for (int kt = 0; kt < nkt; ++kt) {
        const int slot = kt & 1;
        if (kt + 1 < nkt) stage(kt + 1, slot ^ 1);
        const ushort_t* As = &Asm[slot][0];
        const ushort_t* Bs = &Bsm[slot][0];
#pragma unroll
        for (int ks = 0; ks < 2; ++ks) {
            bf16x8 af[4], bf[2];
#pragma unroll
            for (int mi = 0; mi < 4; ++mi) {
                int row = wm * 64 + mi * 16 + r;
                af[mi] = *(const bf16x8*)(As + row * 64 + (((ks * 4 + g) ^ (row & 7)) * 8));
            }
#pragma unroll
            for (int ni = 0; ni < 2; ++ni) {
                int row = wn * 32 + ni * 16 + r;
                bf[ni] = *(const bf16x8*)(Bs + row * 64 + (((ks * 4 + g) ^ (row & 7)) * 8));
            }
            __builtin_amdgcn_s_setprio(1);
#pragma unroll
            for (int mi = 0; mi < 4; ++mi)
#pragma unroll
                for (int ni = 0; ni < 2; ++ni)
                    acc[mi][ni] = __builtin_amdgcn_mfma_f32_16x16x32_bf16(af[mi], bf[ni], acc[mi][ni], 0, 0, 0);
            __builtin_amdgcn_s_setprio(0);
        }
        asm volatile("s_waitcnt vmcnt(0)" ::: "memory");
        __builtin_amdgcn_s_barrier();
        asm volatile("" ::: "memory");
    }

#pragma unroll
    for (int mi = 0; mi < 4; mi++)
#pragma unroll
        for (int ni = 0; ni < 2; ni++) {
            int col = n0 + wn * 32 + ni * 16 + r;
            float bv = bias[col];
#pragma unroll
            for (int reg = 0; reg < 4; reg++) {
                int row = m0 + wm * 64 + mi * 16 + g * 4 + reg;
                C[(size_t)row * N + col] = acc[mi][ni][reg] + bv;
            }
        }
}

// ---------------- RMSNorm + RoPE + scatter (vectorized, coalesced V-transpose) ---
__global__ __launch_bounds__(256) void norm_rope_k(const ushort_t* __restrict__ qkv,
                                                   const float* __restrict__ pe,
                                                   const float* __restrict__ qnw,
                                                   const float* __restrict__ knw,
                                                   ushort_t* __restrict__ qh,
                                                   ushort_t* __restrict__ kh,
                                                   ushort_t* __restrict__ vT) {
    __shared__ ushort_t T[64][68];
    const int tid = threadIdx.x;
    const int lane = tid & 63, w = tid >> 6;
    const int rg = lane >> 4;
    const int d4 = (lane & 15) * 4;
    const int l0 = blockIdx.x * 64;
    const int t  = blockIdx.y;
    const int bh = blockIdx.z;
    const int b = bh >> 4, h = bh & 15;

    if (t == 2) {  // V: bf16 copy + transpose through LDS
#pragma unroll
        for (int i = 0; i < 4; ++i) {
            int ll = w * 16 + rg + 4 * i;
            int m = b * 2048 + l0 + ll;
            ushort4 v = *(const ushort4*)(qkv + (size_t)m * 3072 + 2048 + h * 64 + d4);
            *(ushort4*)(&T[ll][d4]) = v;
        }
        __syncthreads();
        const int d = tid >> 2, lq = (tid & 3) * 16;
        ushort_t* dst = vT + ((size_t)(bh * 64 + d)) * 2048 + l0 + lq;
#pragma unroll
        for (int c = 0; c < 4; ++c) {
            ushort4 o;
            o.x = T[lq + c * 4 + 0][d];
            o.y = T[lq + c * 4 + 1][d];
            o.z = T[lq + c * 4 + 2][d];
            o.w = T[lq + c * 4 + 3][d];
            *(ushort4*)(dst + c * 4) = o;
        }
        return;
    }

    const float* nwp = (t == 0) ? qnw : knw;
    const float4 nwv = *(const float4*)(nwp + d4);
    ushort_t* dst = (t == 0) ? qh : kh;
    const float qscale = (t == 0) ? 0.125f : 1.0f;
#pragma unroll
    for (int i = 0; i < 4; ++i) {
        int ll = w * 16 + rg + 4 * i;
        int l = l0 + ll;
        int m = b * 2048 + l;
        ushort4 vv = *(const ushort4*)(qkv + (size_t)m * 3072 + t * 1024 + h * 64 + d4);
        float v0 = bf2f(vv.x), v1 = bf2f(vv.y), v2 = bf2f(vv.z), v3 = bf2f(vv.w);
        float ss = v0 * v0 + v1 * v1 + v2 * v2 + v3 * v3;
        ss += __shfl_xor(ss, 1, 64);
        ss += __shfl_xor(ss, 2, 64);
        ss += __shfl_xor(ss, 4, 64);
        ss += __shfl_xor(ss, 8, 64);
        float rms = rsqrtf(ss * (1.0f / 64.0f) + EPSV);
        v0 *= rms * nwv.x; v1 *= rms * nwv.y; v2 *= rms * nwv.z; v3 *= rms * nwv.w;
        float4 p0 = *(const float4*)(pe + (size_t)l * 128 + 2 * d4);
        float4 p1 = *(const float4*)(pe + (size_t)l * 128 + 2 * d4 + 4);
        float o0 = (p0.x * v0 + p0.y * v1) * qscale;
        float o1 = (p0.z * v0 + p0.w * v1) * qscale;
        float o2 = (p1.x * v2 + p1.y * v3) * qscale;
        float o3 = (p1.z * v2 + p1.w * v3) * qscale;
        ushort4 o;
        o.x = f2bf(o0); o.y = f2bf(o1); o.z = f2bf(o2); o.w = f2bf(o3);
        *(ushort4*)(dst + ((size_t)bh * 2048 + l) * 64 + d4) = o;
    }
}

// ---------------- Flash attention v2 + defer-max (T13) + cvt_pk P-pack ----------
__global__ __launch_bounds__(256, 2) void attn_k(const ushort_t* __restrict__ qh,
                                                 const ushort_t* __restrict__ kh,
                                                 const ushort_t* __restrict__ vT,
                                                 ushort_t* __restrict__ ob) {
    __shared__ __attribute__((aligned(16))) ushort_t Ksm[2][64 * 64];
    __shared__ __attribute__((aligned(16))) ushort_t Vsm[2][64 * 64];
    __shared__ __attribute__((aligned(16))) ushort_t Plds[4][2][16 * 64];

    const int tid = threadIdx.x;
    const int lane = tid & 63, wid = tid >> 6;
    const int r = lane & 15, g = lane >> 4;
    const int qt = blockIdx.x, bh = blockIdx.y;
    const int q0 = qt * 128 + wid * 32;
    const ushort_t* Q  = qh + (size_t)bh * LL * 64;
    const ushort_t* Kb = kh + (size_t)bh * LL * 64;
    const ushort_t* Vt = vT + (size_t)bh * 64 * LL;

    int row_[2], ccx_[2];
#pragma unroll
    for (int q = 0; q < 2; ++q) {
        int c = q * 256 + tid;
        row_[q] = c >> 3;
        ccx_[q] = (c & 7) ^ (row_[q] & 7);
    }
    const int swz = (r & 7) * 8;

    bf16x8 qf[2][2];
#pragma unroll
    for (int mf = 0; mf < 2; ++mf)
#pragma unroll
        for (int hf = 0; hf < 2; ++hf)
            qf[mf][hf] = *(const bf16x8*)(Q + (size_t)(q0 + mf * 16 + r) * 64 + hf * 32 + g * 8);

    f32x4 acc[2][4] = {};
    float mrow[2] = {-1e30f, -1e30f};
    float srow[2] = {0.f, 0.f};
    const f32x4 zero = {};

#pragma unroll
    for (int q = 0; q < 2; ++q) {
        __builtin_amdgcn_global_load_lds(
            (const __attribute__((address_space(1))) void*)(Kb + (size_t)row_[q] * 64 + ccx_[q] * 8),
            (__attribute__((address_space(3))) void*)(&Ksm[0][0] + (q * 256 + wid * 64) * 8), 16, 0, 0);
        __builtin_amdgcn_global_load_lds(
            (const __attribute__((address_space(1))) void*)(Vt + (size_t)row_[q] * 2048 + ccx_[q] * 8),
            (__attribute__((address_space(3))) void*)(&Vsm[0][0] + (q * 256 + wid * 64) * 8), 16, 0, 0);
    }
    __syncthreads();

    int buf = 0;
    for (int it = 0; it < 32; ++it) {
        if (it < 31) {
            int kvn = (it + 1) * 64;
#pragma unroll
            for (int q = 0; q < 2; ++q) {
                __builtin_amdgcn_global_load_lds(
                    (const __attribute__((address_space(1))) void*)(Kb + (size_t)(kvn + row_[q]) * 64 + ccx_[q] * 8),
                    (__attribute__((address_space(3))) void*)(&Ksm[buf ^ 1][0] + (q * 256 + wid * 64) * 8), 16, 0, 0);
                __builtin_amdgcn_global_load_lds(
                    (const __attribute__((address_space(1))) void*)(Vt + (size_t)row_[q] * 2048 + kvn + ccx_[q] * 8),
                    (__attribute__((address_space(3))) void*)(&Vsm[buf ^ 1][0] + (q * 256 + wid * 64) * 8), 16, 0, 0);
            }
        }
        const ushort_t* Kl = &Ksm[buf][0];
        const ushort_t* Vl = &Vsm[buf][0];

        bf16x8 kf[4][2];
#pragma unroll
        for (int kt = 0; kt < 4; ++kt)
#pragma unroll
            for (int hf = 0; hf < 2; ++hf)
                kf[kt][hf] = *(const bf16x8*)(Kl + (kt * 16 + r) * 64 + (((hf * 4 + g) * 8) ^ swz));

        f32x4 s[2][4];
        __builtin_amdgcn_s_setprio(1);
#pragma unroll
        for (int mf = 0; mf < 2; ++mf)
#pragma unroll
            for (int kt = 0; kt < 4; ++kt) {
                f32x4 t0 = __builtin_amdgcn_mfma_f32_16x16x32_bf16(kf[kt][0], qf[mf][0], zero, 0, 0, 0);
                s[mf][kt] = __builtin_amdgcn_mfma_f32_16x16x32_bf16(kf[kt][1], qf[mf][1], t0, 0, 0, 0);
            }
        __builtin_amdgcn_s_setprio(0);

#pragma unroll
        for (int mf = 0; mf < 2; ++mf) {
            float pm = -1e30f;
#pragma unroll
            for (int kt = 0; kt < 4; ++kt)
#pragma unroll
                for (int reg = 0; reg < 4; ++reg) pm = fmaxf(pm, s[mf][kt][reg]);
            pm = fmaxf(pm, __shfl_xor(pm, 16, 64));
            pm = fmaxf(pm, __shfl_xor(pm, 32, 64));
            bool skip = (__all(pm <= mrow[mf] + 8.0f) != 0);
            float mn, al;
            if (skip) {
                mn = mrow[mf];
            } else {
                mn = fmaxf(mrow[mf], pm);
                al = __expf(mrow[mf] - mn);
                mrow[mf] = mn;
            }
            float rs = 0.f;
#pragma unroll
            for (int kt = 0; kt < 4; ++kt)
#pragma unroll
                for (int reg = 0; reg < 4; ++reg) {
                    float p = __expf(s[mf][kt][reg] - mn);
                    s[mf][kt][reg] = p;
                    rs += p;
                }
            rs += __shfl_xor(rs, 16, 64);
            rs += __shfl_xor(rs, 32, 64);
            if (skip) {
                srow[mf] += rs;
            } else {
                srow[mf] = srow[mf] * al + rs;
                float ab[4];
#pragma unroll
                for (int reg = 0; reg < 4; ++reg) ab[reg] = __shfl(al, g * 4 + reg, 16);
#pragma unroll
                for (int dt = 0; dt < 4; ++dt)
#pragma unroll
                    for (int reg = 0; reg < 4; ++reg) acc[mf][dt][reg] *= ab[reg];
            }
            // P -> LDS via v_cvt_pk_bf16_f32 (2 elems/inst, RNE — replaces ~5-op f2bf)
#pragma unroll
            for (int kt = 0; kt < 4; ++kt) {
                uint2 pw;
                pw.x = cvt_pk_bf16(s[mf][kt][0], s[mf][kt][1]);
                pw.y = cvt_pk_bf16(s[mf][kt][2], s[mf][kt][3]);
                *(uint2*)((ushort_t*)&Plds[wid][mf][0] + r * 64 + (((2 * kt + (g >> 1)) * 8) ^ swz) + (g & 1) * 4) = pw;
            }
        }
        asm volatile("s_waitcnt lgkmcnt(0)" ::: "memory");
        __builtin_amdgcn_sched_barrier(0);

        bf16x8 pa[2][2];
#pragma unroll
        for (int mf = 0; mf < 2; ++mf)
#pragma unroll
            for (int hf = 0; hf < 2; ++hf)
                pa[mf][hf] = *(const bf16x8*)(&Plds[wid][mf][0] + r * 64 + (((hf * 4 + g) * 8) ^ swz));

        __builtin_amdgcn_s_setprio(1);
#pragma unroll
        for (int dt = 0; dt < 4; ++dt)
#pragma unroll
            for (int hv = 0; hv < 2; ++hv) {
                bf16x8 vf = *(const bf16x8*)(Vl + (dt * 16 + r) * 64 + (((hv * 4 + g) * 8) ^ swz));
#pragma unroll
                for (int mf = 0; mf < 2; ++mf)
                    acc[mf][dt] = __builtin_amdgcn_mfma_f32_16x16x32_bf16(pa[mf][hv], vf, acc[mf][dt], 0, 0, 0);
            }
        __builtin_amdgcn_s_setprio(0);

        __syncthreads();
        buf ^= 1;
    }

    int b = bh >> 4, h = bh & 15;
#pragma unroll
    for (int mf = 0; mf < 2; ++mf) {
        float sinv = 1.0f / srow[mf];
        float sb[4];
#pragma unroll
        for (int reg = 0; reg < 4; ++reg) sb[reg] = __shfl(sinv, g * 4 + reg, 16);
#pragma unroll
        for (int dt = 0; dt < 4; ++dt)
#pragma unroll
            for (int reg = 0; reg < 4; ++reg) {
                int l = q0 + mf * 16 + g * 4 + reg;
                ob[((size_t)(b * 2048 + l)) * 1024 + h * 64 + dt * 16 + r] =
                    f2bf(acc[mf][dt][reg] * sb[reg]);
            }
    }
}

// ---------------- launcher ----------------
extern "C" void kernel_launch(void* const* d_in, const int* in_sizes, int n_in,
                              void* d_out, int out_size, void* d_ws, size_t ws_size,
                              hipStream_t stream) {
    const float* x      = (const float*)d_in[0];
    const float* pe     = (const float*)d_in[1];
    const float* qkv_w  = (const float*)d_in[2];
    const float* qkv_b  = (const float*)d_in[3];
    const float* qnw    = (const float*)d_in[4];
    const float* knw    = (const float*)d_in[5];
    const float* proj_w = (const float*)d_in[6];
    const float* proj_b = (const float*)d_in[7];
    float* out = (float*)d_out;

    char* ws = (char*)d_ws;
    ushort_t* xb    = (ushort_t*)(ws);                         // 8 MB
    ushort_t* wqkv  = (ushort_t*)(ws + 8388608);               // 6 MB
    ushort_t* wproj = (ushort_t*)(ws + 8388608 + 6291456);     // 2 MB
    ushort_t* qkvb  = (ushort_t*)(ws + 16777216);              // 24 MB
    ushort_t* qhp   = (ushort_t*)(ws + 16777216 + 25165824);   // 8 MB
    ushort_t* khp   = (ushort_t*)(ws + 16777216 + 25165824 + 8388608);
    ushort_t* vtp   = (ushort_t*)(ws + 16777216 + 25165824 + 2 * 8388608);
    ushort_t* obp   = qkvb;  // reuse qkv region

    const int na = MTOT * DIM, nb = 3 * DIM * DIM, nc = DIM * DIM;
    cvt_all_k<<<(na + nb + nc) / 1024, 256, 0, stream>>>(x, na, qkv_w, nb, proj_w,
                                                         xb, wqkv, wproj);

    // QKV GEMM: 128^2 dbuf, grid (24, 32) = 768 blocks (~3 blocks/CU in flight)
    gemm128<<<dim3(3 * DIM / 128, MTOT / 128), 256, 0, stream>>>(xb, wqkv, qkv_b, qkvb,
                                                                 MTOT, 3 * DIM, DIM);
    norm_rope_k<<<dim3(32, 3, 32), 256, 0, stream>>>(qkvb, pe, qnw, knw, qhp, khp, vtp);
    attn_k<<<dim3(16, 32), 256, 0, stream>>>(qhp, khp, vtp, obp);
    // proj GEMM: 128x64 dbuf, grid (16, 32) = 512 blocks (2 blocks/CU)
    gemm_pj<<<dim3(DIM / 64, MTOT / 128), 256, 0, stream>>>(obp, wproj, proj_b, out,
                                                            MTOT, DIM, DIM);
}

// Round 8
// 211.305 us; speedup vs baseline: 1.1100x; 1.0299x over previous
//
#include <hip/hip_runtime.h>
#include <hip/hip_bf16.h>

#define DIM   1024
#define HEADS 16
#define HD    64
#define BB    2
#define LL    2048
#define MTOT  (BB*LL)   // 4096
#define EPSV  1.1920928955078125e-07f
#define QSCALE 0.18033688011112042f   // 0.125 * log2(e) — softmax runs in exp2 domain
#define THR2   11.541560327111707f    // 8 * log2(e)

typedef __attribute__((ext_vector_type(8))) short bf16x8;
typedef __attribute__((ext_vector_type(4))) float f32x4;
typedef unsigned short ushort_t;

__device__ __forceinline__ float bf2f(ushort_t u) {
    unsigned int x = ((unsigned int)u) << 16;
    return __builtin_bit_cast(float, x);
}
__device__ __forceinline__ ushort_t f2bf(float f) {
    unsigned int x = __builtin_bit_cast(unsigned int, f);
    unsigned int r = (x + 0x7FFFu + ((x >> 16) & 1u)) >> 16;
    return (ushort_t)r;
}
__device__ __forceinline__ unsigned int cvt_pk_bf16(float lo, float hi) {
    unsigned int r;
    asm("v_cvt_pk_bf16_f32 %0, %1, %2" : "=v"(r) : "v"(lo), "v"(hi));
    return r;
}
__device__ __forceinline__ float exp2_fast(float x) {  // v_exp_f32: D = 2^S0
    float r;
    asm("v_exp_f32 %0, %1" : "=v"(r) : "v"(x));
    return r;
}

// ---------------- fused fp32 -> bf16 converts (x, qkv_w, proj_w) ----------------
__global__ __launch_bounds__(256) void cvt_all_k(const float* __restrict__ a, int na,
                                                 const float* __restrict__ b, int nb,
                                                 const float* __restrict__ c,
                                                 ushort_t* __restrict__ oa,
                                                 ushort_t* __restrict__ ob,
                                                 ushort_t* __restrict__ oc) {
    int i = (blockIdx.x * 256 + threadIdx.x) * 4;
    const float* src;
    ushort_t* dst;
    int off;
    if (i < na)            { src = a; dst = oa; off = i; }
    else if (i < na + nb)  { src = b; dst = ob; off = i - na; }
    else                   { src = c; dst = oc; off = i - na - nb; }
    float4 v = *(const float4*)(src + off);
    ushort4 o;
    o.x = f2bf(v.x); o.y = f2bf(v.y); o.z = f2bf(v.z); o.w = f2bf(v.w);
    *(ushort4*)(dst + off) = o;
}

// ------------- QKV GEMM 128x128 dbuf + fused RMSNorm/RoPE/scatter epilogue -------
// A = xb [4096x1024], Bt = wqkv [3072x1024]. Grid (24, 32). Each wave's 64x64
// output tile = one head x 64 rows -> norm/rope in-register; V transposed via LDS.
__global__ __launch_bounds__(256, 2) void gemm_qkv_fused(const ushort_t* __restrict__ A,
                                                         const ushort_t* __restrict__ Bt,
                                                         const float* __restrict__ bias,
                                                         const float* __restrict__ pe,
                                                         const float* __restrict__ qnw,
                                                         const float* __restrict__ knw,
                                                         ushort_t* __restrict__ qh,
                                                         ushort_t* __restrict__ kh,
                                                         ushort_t* __restrict__ vT) {
    __shared__ __attribute__((aligned(16))) ushort_t smem[32768];  // Asm|Bsm, 64 KB
    const int K = 1024;
    const int tid = threadIdx.x;
    const int lane = tid & 63, wid = tid >> 6;
    const int wm = wid >> 1, wn = wid & 1;
    const int r = lane & 15, g = lane >> 4;
    const int m0 = blockIdx.y * 128, n0 = blockIdx.x * 128;

    int srow[4], sgx[4];
#pragma unroll
    for (int p = 0; p < 4; ++p) {
        int c = p * 256 + tid;
        srow[p] = c >> 3;
        sgx[p] = ((c & 7) ^ (srow[p] & 7)) * 8;
    }
    const ushort_t *pa[4], *pb[4];
#pragma unroll
    for (int p = 0; p < 4; ++p) {
        pa[p] = A + (size_t)(m0 + srow[p]) * K + sgx[p];
        pb[p] = Bt + (size_t)(n0 + srow[p]) * K + sgx[p];
    }

    f32x4 acc[4][4] = {};

    auto stage = [&](int kt, int slot) {
        const int kc = kt * 64;
#pragma unroll
        for (int p = 0; p < 4; ++p) {
            __builtin_amdgcn_global_load_lds(
                (const __attribute__((address_space(1))) void*)(pa[p] + kc),
                (__attribute__((address_space(3))) void*)(smem + slot * 8192 + (p * 256 + wid * 64) * 8), 16, 0, 0);
            __builtin_amdgcn_global_load_lds(
                (const __attribute__((address_space(1))) void*)(pb[p] + kc),
                (__attribute__((address_space(3))) void*)(smem + 16384 + slot * 8192 + (p * 256 + wid * 64) * 8), 16, 0, 0);
        }
    };

    stage(0, 0);
    asm volatile("s_waitcnt vmcnt(0)" ::: "memory");
    __builtin_amdgcn_s_barrier();
    asm volatile("" ::: "memory");

    for (int kt = 0; kt < 16; ++kt) {
        const int slot = kt & 1;
        if (kt + 1 < 16) stage(kt + 1, slot ^ 1);
        const ushort_t* As = smem + slot * 8192;
        const ushort_t* Bs = smem + 16384 + slot * 8192;
#pragma unroll
        for (int ks = 0; ks < 2; ++ks) {
            bf16x8 af[4], bf[4];
#pragma unroll
            for (int mi = 0; mi < 4; ++mi) {
                int row = wm * 64 + mi * 16 + r;
                af[mi] = *(const bf16x8*)(As + row * 64 + (((ks * 4 + g) ^ (row & 7)) * 8));
            }
#pragma unroll
            for (int ni = 0; ni < 4; ++ni) {
                int row = wn * 64 + ni * 16 + r;
                bf[ni] = *(const bf16x8*)(Bs + row * 64 + (((ks * 4 + g) ^ (row & 7)) * 8));
            }
            __builtin_amdgcn_s_setprio(1);
#pragma unroll
            for (int mi = 0; mi < 4; ++mi)
#pragma unroll
                for (int ni = 0; ni < 4; ++ni)
                    acc[mi][ni] = __builtin_amdgcn_mfma_f32_16x16x32_bf16(af[mi], bf[ni], acc[mi][ni], 0, 0, 0);
            __builtin_amdgcn_s_setprio(0);
        }
        asm volatile("s_waitcnt vmcnt(0)" ::: "memory");
        __builtin_amdgcn_s_barrier();
        asm volatile("" ::: "memory");
    }

    // ---- fused epilogue ----
    const int t = n0 >> 10;                      // 0=Q 1=K 2=V
    const int h = ((n0 & 1023) >> 6) + wn;       // head of this wave
    const int b = m0 >> 11;
    const int bh = b * 16 + h;
    const int l0 = (m0 & 2047) + wm * 64;        // within-batch row base of this wave

    float bv[4];
#pragma unroll
    for (int ni = 0; ni < 4; ++ni) bv[ni] = bias[n0 + wn * 64 + ni * 16 + r];
#pragma unroll
    for (int mi = 0; mi < 4; ++mi)
#pragma unroll
        for (int ni = 0; ni < 4; ++ni)
#pragma unroll
            for (int reg = 0; reg < 4; ++reg) acc[mi][ni][reg] += bv[ni];

    if (t < 2) {  // Q / K: RMSNorm + RoPE + head-major store
        const float* nw = (t == 0) ? qnw : knw;
        float nwv[4];
#pragma unroll
        for (int ni = 0; ni < 4; ++ni) nwv[ni] = nw[ni * 16 + r];
        const float qsc = (t == 0) ? QSCALE : 1.0f;
        ushort_t* dst = ((t == 0) ? qh : kh) + (size_t)bh * 2048 * 64;
#pragma unroll
        for (int mi = 0; mi < 4; ++mi)
#pragma unroll
            for (int reg = 0; reg < 4; ++reg) {
                float ss = 0.f;
#pragma unroll
                for (int ni = 0; ni < 4; ++ni) {
                    float xv = acc[mi][ni][reg];
                    ss = fmaf(xv, xv, ss);
                }
                ss += __shfl_xor(ss, 1, 64);
                ss += __shfl_xor(ss, 2, 64);
                ss += __shfl_xor(ss, 4, 64);
                ss += __shfl_xor(ss, 8, 64);
                float rms = rsqrtf(ss * (1.0f / 64.0f) + EPSV);
                int l = l0 + mi * 16 + g * 4 + reg;
                const float* per = pe + (size_t)l * 128 + 2 * r;
#pragma unroll
                for (int ni = 0; ni < 4; ++ni) {
                    float nv = acc[mi][ni][reg] * rms * nwv[ni];
                    float partner = __shfl_xor(nv, 1, 64);
                    float2 pv = *(const float2*)(per + ni * 32);
                    float e0 = (r & 1) ? partner : nv;
                    float e1 = (r & 1) ? nv : partner;
                    dst[(size_t)l * 64 + ni * 16 + r] = f2bf((pv.x * e0 + pv.y * e1) * qsc);
                }
            }
    } else {  // V: per-wave LDS transpose -> vT[bh][d][l]
        ushort_t* T = smem + wid * 4352;         // 64 x 66 (padded), per-wave region
#pragma unroll
        for (int mi = 0; mi < 4; ++mi)
#pragma unroll
            for (int ni = 0; ni < 4; ++ni)
#pragma unroll
                for (int reg = 0; reg < 4; ++reg)
                    T[(mi * 16 + g * 4 + reg) * 66 + ni * 16 + r] = f2bf(acc[mi][ni][reg]);
        asm volatile("s_waitcnt lgkmcnt(0)" ::: "memory");
        const int dd = lane >> 2, lq = (lane & 3) * 16;
#pragma unroll
        for (int pass = 0; pass < 4; ++pass) {
            int d = pass * 16 + dd;
            ushort_t* dst = vT + ((size_t)(bh * 64 + d)) * 2048 + (m0 & 2047) + wm * 64 + lq;
#pragma unroll
            for (int c = 0; c < 4; ++c) {
                ushort4 o;
                o.x = T[(lq + c * 4 + 0) * 66 + d];
                o.y = T[(lq + c * 4 + 1) * 66 + d];
                o.z = T[(lq + c * 4 + 2) * 66 + d];
                o.w = T[(lq + c * 4 + 3) * 66 + d];
                *(ushort4*)(dst + c * 4) = o;
            }
        }
    }
}

// ---------------- proj GEMM 128x64, BK=64, dbuf, f32 out (grid 512 = 2/CU) ------
__global__ __launch_bounds__(256, 2) void gemm_pj(const ushort_t* __restrict__ A,
                                                  const ushort_t* __restrict__ Bt,
                                                  const float* __restrict__ bias,
                                                  float* __restrict__ C,
                                                  int M, int N, int K) {
    __shared__ __attribute__((aligned(16))) ushort_t Asm[2][128 * 64];
    __shared__ __attribute__((aligned(16))) ushort_t Bsm[2][64 * 64];
    const int tid = threadIdx.x;
    const int lane = tid & 63, wid = tid >> 6;
    const int wm = wid >> 1, wn = wid & 1;
    const int r = lane & 15, g = lane >> 4;
    const int m0 = blockIdx.y * 128, n0 = blockIdx.x * 64;

    int srow[4], sgx[4];
#pragma unroll
    for (int p = 0; p < 4; ++p) {
        int c = p * 256 + tid;
        srow[p] = c >> 3;
        sgx[p] = ((c & 7) ^ (srow[p] & 7)) * 8;
    }
    const ushort_t *pa[4], *pb[2];
#pragma unroll
    for (int p = 0; p < 4; ++p) pa[p] = A + (size_t)(m0 + srow[p]) * K + sgx[p];
#pragma unroll
    for (int p = 0; p < 2; ++p) pb[p] = Bt + (size_t)(n0 + srow[p]) * K + sgx[p];

    f32x4 acc[4][2] = {};

    auto stage = [&](int kt, int slot) {
        const int kc = kt * 64;
#pragma unroll
        for (int p = 0; p < 4; ++p)
            __builtin_amdgcn_global_load_lds(
                (const __attribute__((address_space(1))) void*)(pa[p] + kc),
                (__attribute__((address_space(3))) void*)(&Asm[slot][0] + (p * 256 + wid * 64) * 8), 16, 0, 0);
#pragma unroll
        for (int p = 0; p < 2; ++p)
            __builtin_amdgcn_global_load_lds(
                (const __attribute__((address_space(1))) void*)(pb[p] + kc),
                (__attribute__((address_space(3))) void*)(&Bsm[slot][0] + (p * 256 + wid * 64) * 8), 16, 0, 0);
    };

    stage(0, 0);
    asm volatile("s_waitcnt vmcnt(0)" ::: "memory");
    __builtin_amdgcn_s_barrier();
    asm volatile("" ::: "memory");

    const int nkt = K >> 6;
    for (int kt = 0; kt < nkt; ++kt) {
        const int slot = kt & 1;
        if (kt + 1 < nkt) stage(kt + 1, slot ^ 1);
        const ushort_t* As = &Asm[slot][0];
        const ushort_t* Bs = &Bsm[slot][0];
#pragma unroll
        for (int ks = 0; ks < 2; ++ks) {
            bf16x8 af[4], bf[2];
#pragma unroll
            for (int mi = 0; mi < 4; ++mi) {
                int row = wm * 64 + mi * 16 + r;
                af[mi] = *(const bf16x8*)(As + row * 64 + (((ks * 4 + g) ^ (row & 7)) * 8));
            }
#pragma unroll
            for (int ni = 0; ni < 2; ++ni) {
                int row = wn * 32 + ni * 16 + r;
                bf[ni] = *(const bf16x8*)(Bs + row * 64 + (((ks * 4 + g) ^ (row & 7)) * 8));
            }
            __builtin_amdgcn_s_setprio(1);
#pragma unroll
            for (int mi = 0; mi < 4; ++mi)
#pragma unroll
                for (int ni = 0; ni < 2; ++ni)
                    acc[mi][ni] = __builtin_amdgcn_mfma_f32_16x16x32_bf16(af[mi], bf[ni], acc[mi][ni], 0, 0, 0);
            __builtin_amdgcn_s_setprio(0);
        }
        asm volatile("s_waitcnt vmcnt(0)" ::: "memory");
        __builtin_amdgcn_s_barrier();
        asm volatile("" ::: "memory");
    }

#pragma unroll
    for (int mi = 0; mi < 4; mi++)
#pragma unroll
        for (int ni = 0; ni < 2; ni++) {
            int col = n0 + wn * 32 + ni * 16 + r;
            float bvv = bias[col];
#pragma unroll
            for (int reg = 0; reg < 4; reg++) {
                int row = m0 + wm * 64 + mi * 16 + g * 4 + reg;
                C[(size_t)row * N + col] = acc[mi][ni][reg] + bvv;
            }
        }
}

// ---------------- Flash attention: exp2-domain softmax + defer-max + cvt_pk -----
__global__ __launch_bounds__(256, 2) void attn_k(const ushort_t* __restrict__ qh,
                                                 const ushort_t* __restrict__ kh,
                                                 const ushort_t* __restrict__ vT,
                                                 ushort_t* __restrict__ ob) {
    __shared__ __attribute__((aligned(16))) ushort_t Ksm[2][64 * 64];
    __shared__ __attribute__((aligned(16))) ushort_t Vsm[2][64 * 64];
    __shared__ __attribute__((aligned(16))) ushort_t Plds[4][2][16 * 64];

    const int tid = threadIdx.x;
    const int lane = tid & 63, wid = tid >> 6;
    const int r = lane & 15, g = lane >> 4;
    const int qt = blockIdx.x, bh = blockIdx.y;
    const int q0 = qt * 128 + wid * 32;
    const ushort_t* Q  = qh + (size_t)bh * LL * 64;
    const ushort_t* Kb = kh + (size_t)bh * LL * 64;
    const ushort_t* Vt = vT + (size_t)bh * 64 * LL;

    int row_[2], ccx_[2];
#pragma unroll
    for (int q = 0; q < 2; ++q) {
        int c = q * 256 + tid;
        row_[q] = c >> 3;
        ccx_[q] = (c & 7) ^ (row_[q] & 7);
    }
    const int swz = (r & 7) * 8;

    bf16x8 qf[2][2];
#pragma unroll
    for (int mf = 0; mf < 2; ++mf)
#pragma unroll
        for (int hf = 0; hf < 2; ++hf)
            qf[mf][hf] = *(const bf16x8*)(Q + (size_t)(q0 + mf * 16 + r) * 64 + hf * 32 + g * 8);

    f32x4 acc[2][4] = {};
    float mrow[2] = {-1e30f, -1e30f};
    float srow[2] = {0.f, 0.f};
    const f32x4 zero = {};

#pragma unroll
    for (int q = 0; q < 2; ++q) {
        __builtin_amdgcn_global_load_lds(
            (const __attribute__((address_space(1))) void*)(Kb + (size_t)row_[q] * 64 + ccx_[q] * 8),
            (__attribute__((address_space(3))) void*)(&Ksm[0][0] + (q * 256 + wid * 64) * 8), 16, 0, 0);
        __builtin_amdgcn_global_load_lds(
            (const __attribute__((address_space(1))) void*)(Vt + (size_t)row_[q] * 2048 + ccx_[q] * 8),
            (__attribute__((address_space(3))) void*)(&Vsm[0][0] + (q * 256 + wid * 64) * 8), 16, 0, 0);
    }
    __syncthreads();

    int buf = 0;
    for (int it = 0; it < 32; ++it) {
        if (it < 31) {
            int kvn = (it + 1) * 64;
#pragma unroll
            for (int q = 0; q < 2; ++q) {
                __builtin_amdgcn_global_load_lds(
                    (const __attribute__((address_space(1))) void*)(Kb + (size_t)(kvn + row_[q]) * 64 + ccx_[q] * 8),
                    (__attribute__((address_space(3))) void*)(&Ksm[buf ^ 1][0] + (q * 256 + wid * 64) * 8), 16, 0, 0);
                __builtin_amdgcn_global_load_lds(
                    (const __attribute__((address_space(1))) void*)(Vt + (size_t)row_[q] * 2048 + kvn + ccx_[q] * 8),
                    (__attribute__((address_space(3))) void*)(&Vsm[buf ^ 1][0] + (q * 256 + wid * 64) * 8), 16, 0, 0);
            }
        }
        const ushort_t* Kl = &Ksm[buf][0];
        const ushort_t* Vl = &Vsm[buf][0];

        bf16x8 kf[4][2];
#pragma unroll
        for (int kt = 0; kt < 4; ++kt)
#pragma unroll
            for (int hf = 0; hf < 2; ++hf)
                kf[kt][hf] = *(const bf16x8*)(Kl + (kt * 16 + r) * 64 + (((hf * 4 + g) * 8) ^ swz));

        f32x4 s[2][4];
        __builtin_amdgcn_s_setprio(1);
#pragma unroll
        for (int mf = 0; mf < 2; ++mf)
#pragma unroll
            for (int kt = 0; kt < 4; ++kt) {
                f32x4 t0 = __builtin_amdgcn_mfma_f32_16x16x32_bf16(kf[kt][0], qf[mf][0], zero, 0, 0, 0);
                s[mf][kt] = __builtin_amdgcn_mfma_f32_16x16x32_bf16(kf[kt][1], qf[mf][1], t0, 0, 0, 0);
            }
        __builtin_amdgcn_s_setprio(0);

#pragma unroll
        for (int mf = 0; mf < 2; ++mf) {
            float pm = -1e30f;
#pragma unroll
            for (int kt = 0; kt < 4; ++kt)
#pragma unroll
                for (int reg = 0; reg < 4; ++reg) pm = fmaxf(pm, s[mf][kt][reg]);
            pm = fmaxf(pm, __shfl_xor(pm, 16, 64));
            pm = fmaxf(pm, __shfl_xor(pm, 32, 64));
            bool skip = (__all(pm <= mrow[mf] + THR2) != 0);
            float mn, al;
            if (skip) {
                mn = mrow[mf];
            } else {
                mn = fmaxf(mrow[mf], pm);
                al = exp2_fast(mrow[mf] - mn);
                mrow[mf] = mn;
            }
            float rs = 0.f;
#pragma unroll
            for (int kt = 0; kt < 4; ++kt)
#pragma unroll
                for (int reg = 0; reg < 4; ++reg) {
                    float p = exp2_fast(s[mf][kt][reg] - mn);
                    s[mf][kt][reg] = p;
                    rs += p;
                }
            rs += __shfl_xor(rs, 16, 64);
            rs += __shfl_xor(rs, 32, 64);
            if (skip) {
                srow[mf] += rs;
            } else {
                srow[mf] = srow[mf] * al + rs;
                float ab[4];
#pragma unroll
                for (int reg = 0; reg < 4; ++reg) ab[reg] = __shfl(al, g * 4 + reg, 16);
#pragma unroll
                for (int dt = 0; dt < 4; ++dt)
#pragma unroll
                    for (int reg = 0; reg < 4; ++reg) acc[mf][dt][reg] *= ab[reg];
            }
#pragma unroll
            for (int kt = 0; kt < 4; ++kt) {
                uint2 pw;
                pw.x = cvt_pk_bf16(s[mf][kt][0], s[mf][kt][1]);
                pw.y = cvt_pk_bf16(s[mf][kt][2], s[mf][kt][3]);
                *(uint2*)((ushort_t*)&Plds[wid][mf][0] + r * 64 + (((2 * kt + (g >> 1)) * 8) ^ swz) + (g & 1) * 4) = pw;
            }
        }
        asm volatile("s_waitcnt lgkmcnt(0)" ::: "memory");
        __builtin_amdgcn_sched_barrier(0);

        bf16x8 pa[2][2];
#pragma unroll
        for (int mf = 0; mf < 2; ++mf)
#pragma unroll
            for (int hf = 0; hf < 2; ++hf)
                pa[mf][hf] = *(const bf16x8*)(&Plds[wid][mf][0] + r * 64 + (((hf * 4 + g) * 8) ^ swz));

        __builtin_amdgcn_s_setprio(1);
#pragma unroll
        for (int dt = 0; dt < 4; ++dt)
#pragma unroll
            for (int hv = 0; hv < 2; ++hv) {
                bf16x8 vf = *(const bf16x8*)(Vl + (dt * 16 + r) * 64 + (((hv * 4 + g) * 8) ^ swz));
#pragma unroll
                for (int mf = 0; mf < 2; ++mf)
                    acc[mf][dt] = __builtin_amdgcn_mfma_f32_16x16x32_bf16(pa[mf][hv], vf, acc[mf][dt], 0, 0, 0);
            }
        __builtin_amdgcn_s_setprio(0);

        __syncthreads();
        buf ^= 1;
    }

    int b = bh >> 4, h = bh & 15;
#pragma unroll
    for (int mf = 0; mf < 2; ++mf) {
        float sinv = 1.0f / srow[mf];
        float sb[4];
#pragma unroll
        for (int reg = 0; reg < 4; ++reg) sb[reg] = __shfl(sinv, g * 4 + reg, 16);
#pragma unroll
        for (int dt = 0; dt < 4; ++dt)
#pragma unroll
            for (int reg = 0; reg < 4; ++reg) {
                int l = q0 + mf * 16 + g * 4 + reg;
                ob[((size_t)(b * 2048 + l)) * 1024 + h * 64 + dt * 16 + r] =
                    f2bf(acc[mf][dt][reg] * sb[reg]);
            }
    }
}

// ---------------- launcher ----------------
extern "C" void kernel_launch(void* const* d_in, const int* in_sizes, int n_in,
                              void* d_out, int out_size, void* d_ws, size_t ws_size,
                              hipStream_t stream) {
    const float* x      = (const float*)d_in[0];
    const float* pe     = (const float*)d_in[1];
    const float* qkv_w  = (const float*)d_in[2];
    const float* qkv_b  = (const float*)d_in[3];
    const float* qnw    = (const float*)d_in[4];
    const float* knw    = (const float*)d_in[5];
    const float* proj_w = (const float*)d_in[6];
    const float* proj_b = (const float*)d_in[7];
    float* out = (float*)d_out;

    char* ws = (char*)d_ws;
    ushort_t* xb    = (ushort_t*)(ws);                         // 8 MB
    ushort_t* wqkv  = (ushort_t*)(ws + 8388608);               // 6 MB
    ushort_t* wproj = (ushort_t*)(ws + 8388608 + 6291456);     // 2 MB
    ushort_t* obp   = (ushort_t*)(ws + 16777216);              // attn out, 8 MB used
    ushort_t* qhp   = (ushort_t*)(ws + 16777216 + 25165824);   // 8 MB
    ushort_t* khp   = (ushort_t*)(ws + 16777216 + 25165824 + 8388608);
    ushort_t* vtp   = (ushort_t*)(ws + 16777216 + 25165824 + 2 * 8388608);

    const int na = MTOT * DIM, nb = 3 * DIM * DIM, nc = DIM * DIM;
    cvt_all_k<<<(na + nb + nc) / 1024, 256, 0, stream>>>(x, na, qkv_w, nb, proj_w,
                                                         xb, wqkv, wproj);

    // QKV GEMM + fused norm/rope/scatter: grid (24, 32)
    gemm_qkv_fused<<<dim3(24, 32), 256, 0, stream>>>(xb, wqkv, qkv_b, pe, qnw, knw,
                                                     qhp, khp, vtp);
    attn_k<<<dim3(16, 32), 256, 0, stream>>>(qhp, khp, vtp, obp);
    gemm_pj<<<dim3(DIM / 64, MTOT / 128), 256, 0, stream>>>(obp, wproj, proj_b, out,
                                                            MTOT, DIM, DIM);
}